// Round 11
// baseline (3049.734 us; speedup 1.0000x reference)
//
#include <hip/hip_runtime.h>
#include <cmath>

#define B_ 1024
#define T_ 75
#define IN_ 768
#define H_ 512
#define G_ 2048
#define GRIDN 256

#define EPSF 1e-15f
#define MAXN 0.99999f
#define GTP 136          // padded gt row (u16)
#define CSP 36           // padded csd row (u16)

typedef __bf16 bf16_t;
typedef bf16_t bf16x8 __attribute__((ext_vector_type(8)));
typedef float f32x4 __attribute__((ext_vector_type(4)));
typedef unsigned short u16;
typedef u16 u16x8 __attribute__((ext_vector_type(8)));
typedef u16 u16x4 __attribute__((ext_vector_type(4)));
typedef unsigned long long u64;
typedef u64 u64x2 __attribute__((ext_vector_type(2)));

// ---------------- scalar helpers ----------------

__device__ inline float sigmoidf_(float x) { return 1.0f / (1.0f + expf(-x)); }

__device__ inline u16 f2bf(float f) {
    unsigned u = __builtin_bit_cast(unsigned, f);
    u = u + 0x7FFFu + ((u >> 16) & 1u);
    return (u16)(u >> 16);
}
__device__ inline float bf2f(u16 h) {
    return __builtin_bit_cast(float, (unsigned)h << 16);
}

__device__ inline float tangentize_scale(float n) {
    float n1 = fmaxf(n, EPSF);
    float m = fminf(tanhf(n1), MAXN);
    return atanhf(m) / n1;
}
__device__ inline float expproj_scale(float n) {
    float n1 = fmaxf(n, EPSF);
    return fminf(tanhf(n1), MAXN) / n1;
}

__device__ inline float blockReduceSum(float v) {
    __shared__ float sm[8];
    __syncthreads();
    #pragma unroll
    for (int off = 32; off > 0; off >>= 1) v += __shfl_down(v, off, 64);
    int w = threadIdx.x >> 6, lane = threadIdx.x & 63;
    if (lane == 0) sm[w] = v;
    __syncthreads();
    int nw = (blockDim.x + 63) >> 6;
    if (threadIdx.x == 0) {
        float r = sm[0];
        for (int i = 1; i < nw; ++i) r += sm[i];
        sm[0] = r;
    }
    __syncthreads();
    return sm[0];
}

// ---- agent-scope (sc1) accessors: proven cross-block path ----
__device__ inline void st_agent_u64(void* p, u64 v) {
    __hip_atomic_store((u64*)p, v, __ATOMIC_RELAXED, __HIP_MEMORY_SCOPE_AGENT);
}
__device__ inline void st_agent_u32(unsigned* p, unsigned v) {
    __hip_atomic_store(p, v, __ATOMIC_RELAXED, __HIP_MEMORY_SCOPE_AGENT);
}
__device__ inline void st_agent_f32(float* p, float v) {
    __hip_atomic_store(p, v, __ATOMIC_RELAXED, __HIP_MEMORY_SCOPE_AGENT);
}
__device__ inline void st_agent_u16(u16* p, u16 v) {
    __hip_atomic_store(p, v, __ATOMIC_RELAXED, __HIP_MEMORY_SCOPE_AGENT);
}
__device__ inline u64 ld_agent_u64(const void* p) {
    return __hip_atomic_load((const u64*)p, __ATOMIC_RELAXED, __HIP_MEMORY_SCOPE_AGENT);
}
__device__ inline unsigned ld_agent_u32(const unsigned* p) {
    return __hip_atomic_load(p, __ATOMIC_RELAXED, __HIP_MEMORY_SCOPE_AGENT);
}
__device__ inline float ld_agent_f32(const float* p) {
    return __hip_atomic_load(p, __ATOMIC_RELAXED, __HIP_MEMORY_SCOPE_AGENT);
}
__device__ inline bf16x8 ld_state16(const u16* p) {
    u64x2 t;
    t.x = ld_agent_u64(p);
    t.y = ld_agent_u64(p + 4);
    return __builtin_bit_cast(bf16x8, t);
}
__device__ inline u16x4 ld_state8(const u16* p) {
    return __builtin_bit_cast(u16x4, ld_agent_u64(p));
}

// sc0 16B load: bypasses L0/L1, reads the XCD-shared L2. Result NOT ready
// until a following s_waitcnt vmcnt(0) — caller drains.
__device__ inline f32x4 ld_sc0_16(const u16* p) {
    f32x4 r;
    asm volatile("global_load_dwordx4 %0, %1, off sc0" : "=v"(r) : "v"(p));
    return r;
}

// ---------------- precompute kernels ----------------

__global__ void cvt_f32_bf16(const float* __restrict__ s, u16* __restrict__ d, int n) {
    int i = (blockIdx.x * 256 + threadIdx.x) * 4;
    if (i < n) {
        float4 f = *reinterpret_cast<const float4*>(s + i);
        d[i + 0] = f2bf(f.x); d[i + 1] = f2bf(f.y);
        d[i + 2] = f2bf(f.z); d[i + 3] = f2bf(f.w);
    }
}

__global__ __launch_bounds__(256) void prep_sentb(const float* __restrict__ sent,
                                                  u16* __restrict__ sentb) {
    int bid = blockIdx.x;            // = b*75 + t
    int b = bid / T_, t = bid - b * T_;
    const float* src = sent + (size_t)bid * IN_;
    float v[3]; float ss = 0.f;
    #pragma unroll
    for (int e = 0; e < 3; ++e) { v[e] = src[threadIdx.x + e * 256]; ss += v[e] * v[e]; }
    float tot = blockReduceSum(ss);
    float sc = tangentize_scale(sqrtf(tot));
    u16* dst = sentb + ((size_t)t * B_ + b) * IN_;
    #pragma unroll
    for (int e = 0; e < 3; ++e) dst[threadIdx.x + e * 256] = f2bf(v[e] * sc);
}

__global__ __launch_bounds__(256) void xscale_kernel(const float* __restrict__ x,
                                                     float* __restrict__ xscale) {
    int row = blockIdx.x;
    const float* p = x + (size_t)row * IN_;
    float s = 0.f;
    for (int k = threadIdx.x; k < IN_; k += 256) { float v = p[k]; s += v * v; }
    float tot = blockReduceSum(s);
    if (threadIdx.x == 0) xscale[row] = tangentize_scale(sqrtf(tot));
}

__global__ void tf_kernel(const float* __restrict__ x, float* __restrict__ tf) {
    int b = blockIdx.x;
    float v = (threadIdx.x < T_) ? x[(size_t)b * T_ + threadIdx.x] : 0.f;
    float tot = blockReduceSum(v * v);
    float s = expproj_scale(sqrtf(tot));
    if (threadIdx.x < T_) tf[(size_t)b * T_ + threadIdx.x] = s * v;
}

// ---------------- XU GEMM (t-major) ----------------
template<int F32SRC>
__global__ __launch_bounds__(256) void xu_gemm(const void* __restrict__ Asrc,
    const float* __restrict__ xscale, const u16* __restrict__ W,
    const float* __restrict__ b1, const float* __restrict__ b2, u16* __restrict__ C)
{
    __shared__ __align__(16) unsigned char As[128 * 128];
    __shared__ __align__(16) unsigned char Ws[128 * 128];
    int bid = (int)blockIdx.x;
    bid = (bid & 7) * ((int)gridDim.x >> 3) + (bid >> 3);
    const int bn = (bid % 16) * 128;
    const int bm = (bid / 16) * 128;
    const int tq = bm >> 10;
    const int b0 = bm & 1023;

    const int tid = threadIdx.x;
    const int lane = tid & 63;
    const int wid = tid >> 6;
    const int wr = wid >> 1, wc = wid & 1;
    const int l15 = lane & 15, l4 = lane >> 4;

    f32x4 acc[4][4] = {};

    for (int k0 = 0; k0 < IN_; k0 += 64) {
        __syncthreads();
        #pragma unroll
        for (int c = 0; c < 4; ++c) {
            int ch = c * 256 + tid;
            int r = ch >> 3, q = ch & 7;
            unsigned off = (unsigned)(r * 128 + ((q ^ (r & 7)) * 16));
            if (F32SRC) {
                int b = b0 + r;
                const float* src = (const float*)Asrc + ((size_t)b * T_ + tq) * IN_ + k0 + q * 8;
                float rs = xscale[(size_t)b * T_ + tq];
                float4 f0 = *reinterpret_cast<const float4*>(src);
                float4 f1 = *reinterpret_cast<const float4*>(src + 4);
                u16x8 v;
                v[0] = f2bf(f0.x * rs); v[1] = f2bf(f0.y * rs);
                v[2] = f2bf(f0.z * rs); v[3] = f2bf(f0.w * rs);
                v[4] = f2bf(f1.x * rs); v[5] = f2bf(f1.y * rs);
                v[6] = f2bf(f1.z * rs); v[7] = f2bf(f1.w * rs);
                *reinterpret_cast<u16x8*>(As + off) = v;
            } else {
                const u16* src = (const u16*)Asrc + (size_t)(bm + r) * IN_ + k0 + q * 8;
                *reinterpret_cast<u16x8*>(As + off) = *reinterpret_cast<const u16x8*>(src);
            }
        }
        #pragma unroll
        for (int c = 0; c < 4; ++c) {
            int ch = c * 256 + tid;
            int r = ch >> 3, q = ch & 7;
            unsigned off = (unsigned)(r * 128 + ((q ^ (r & 7)) * 16));
            const u16* src = W + (size_t)(bn + r) * IN_ + k0 + q * 8;
            *reinterpret_cast<u16x8*>(Ws + off) = *reinterpret_cast<const u16x8*>(src);
        }
        __syncthreads();
        #pragma unroll
        for (int ks = 0; ks < 2; ++ks) {
            bf16x8 af[4], bf[4];
            #pragma unroll
            for (int m = 0; m < 4; ++m) {
                int r = wr * 64 + m * 16 + l15;
                af[m] = *reinterpret_cast<const bf16x8*>(As + r * 128 + (((ks * 4 + l4) ^ (r & 7)) * 16));
            }
            #pragma unroll
            for (int n = 0; n < 4; ++n) {
                int r = wc * 64 + n * 16 + l15;
                bf[n] = *reinterpret_cast<const bf16x8*>(Ws + r * 128 + (((ks * 4 + l4) ^ (r & 7)) * 16));
            }
            #pragma unroll
            for (int m = 0; m < 4; ++m)
                #pragma unroll
                for (int n = 0; n < 4; ++n)
                    acc[m][n] = __builtin_amdgcn_mfma_f32_16x16x32_bf16(af[m], bf[n], acc[m][n], 0, 0, 0);
        }
    }

    #pragma unroll
    for (int m = 0; m < 4; ++m)
        #pragma unroll
        for (int n = 0; n < 4; ++n) {
            int col = bn + wc * 64 + n * 16 + l15;
            float bb = b1[col] + b2[col];
            #pragma unroll
            for (int v = 0; v < 4; ++v) {
                int row = bm + wr * 64 + m * 16 + l4 * 4 + v;
                C[(size_t)row * G_ + col] = f2bf(acc[m][n][v] + bb);
            }
        }
}

// ---------------- persistent kernel: encoder weights in REGISTERS ----------------
// Block (bt, ct): rows bt*64.., h-cols ct*32.. ; bid = ct*16 + bt pins group bt to XCD bt%8.
// ENCODER: wave w owns gate tile w; waves 0,1 also own the cs1 tiles. Weight fragments are
// t-invariant -> preloaded ONCE into VGPRs (64 regs gate + 64 regs cs1 for waves 0-1).
// The per-step MFMA loop is pure LDS-A x register-B: zero global loads on the chain.

__global__ __launch_bounds__(512, 2) void persistent9(
    const u16* __restrict__ XU, const float* __restrict__ tf_g,
    const u16* __restrict__ Wall, const u16* __restrict__ Wd, const float* __restrict__ bd,
    const u16* __restrict__ Wih, const u16* __restrict__ Whh,
    const float* __restrict__ b_ih, const float* __restrict__ b_hh,
    const u16* __restrict__ Wfcin, const float* __restrict__ b_fcin,
    const float* __restrict__ Wfco, const float* __restrict__ b_fco,
    const float* __restrict__ Wspan, const float* __restrict__ bspan,
    u16* __restrict__ hb0, u16* __restrict__ hb1,
    u16* __restrict__ cb0, u16* __restrict__ cb1,
    u16* __restrict__ ib0, u16* __restrict__ ib1,
    float* __restrict__ pn,           // [16 bt][16 ct][128] final-norm partials
    unsigned* __restrict__ flags,     // [16 bt][16 ct]  (sc1 / LLC)
    unsigned* __restrict__ flagsF,    // [16 bt][16 ct]  (plain / L2)
    unsigned* __restrict__ xcds,      // [256] per-block XCC id
    float* __restrict__ out)
{
    const int bid = (int)blockIdx.x;
    const int bt = bid & 15, ct = bid >> 4;
    const int r0 = bt * 64, j0 = ct * 32;
    const int tid = threadIdx.x;
    const int lane = tid & 63;
    const int wid = tid >> 6;
    const int m = wid & 3, nh = wid >> 2;   // decoder mapping (unchanged)
    const int l15 = lane & 15, l4 = lane >> 4;

    u16* hb_[2] = {hb0, hb1};
    u16* cb_[2] = {cb0, cb1};
    u16* ib_[2] = {ib0, ib1};

    __shared__ u16 sh_h[64 * 512];    // 64 KB
    __shared__ u16 sh_c[64 * 512];    // 64 KB
    __shared__ u16 gt[64 * GTP];
    __shared__ u16 csd[64 * CSP];
    __shared__ float shs[64], scs[64];
    __shared__ int fastF;

    const int prow = tid >> 3, pe0 = (tid & 7) * 4;

    unsigned epoch = 0;
    unsigned* gflag = flags + bt * 16;
    unsigned* fflag = flagsF + bt * 16;
    bool fastv = false;

    // signal: drain own stores, block-sync, publish epoch on BOTH paths.
    auto gsig = [&]() {
        asm volatile("s_waitcnt vmcnt(0)" ::: "memory");
        __syncthreads();
        ++epoch;
        if (tid == 0) {
            if (fastv) *(volatile unsigned*)(fflag + ct) = epoch;   // L2-path signal
            st_agent_u32(&gflag[ct], epoch);                        // LLC-path (proven)
        }
    };
    // wait: fast sc0 poll with periodic sc1 fallback -> guaranteed liveness.
    auto gwait = [&]() {
        if (tid < 16) {
            if (fastv) {
                unsigned it = 0, v;
                for (;;) {
                    asm volatile("global_load_dword %0, %1, off sc0\n\ts_waitcnt vmcnt(0)"
                                 : "=v"(v) : "v"(fflag + tid) : "memory");
                    if (v >= epoch) break;
                    if ((it++ & 7) == 7 && ld_agent_u32(&gflag[tid]) >= epoch) break;
                    __builtin_amdgcn_s_sleep(1);
                }
            } else {
                while (ld_agent_u32(&gflag[tid]) < epoch) __builtin_amdgcn_s_sleep(1);
            }
        }
        __syncthreads();
    };

    // ---- XCD co-residency detection (epoch 1, pure sc1 protocol) ----
    {
        unsigned xcd = __builtin_amdgcn_s_getreg(6164);  // hwreg(HW_REG_XCC_ID=20,0,4)
        if (tid == 0) st_agent_u32(&xcds[bid], 0x100u | (xcd & 0xFu));
        gsig(); gwait();
        if (tid < 16) {
            unsigned mine = ld_agent_u32(&xcds[(tid << 4) + bt]);
            unsigned ref  = ld_agent_u32(&xcds[bt]);
            u64 b = __ballot(mine == ref);
            if (tid == 0) fastF = ((b & 0xFFFFull) == 0xFFFFull) ? 1 : 0;
        }
        __syncthreads();
        fastv = (fastF != 0);
    }

    // ---- staging of h+c rows r0..r0+63 into LDS (XOR-swizzled), single drain ----
    auto stage = [&](const u16* hsrc, const u16* csrc) {
        const u16* hs = hsrc + (size_t)r0 * 512;
        const u16* cs = csrc + (size_t)r0 * 512;
        if (fastv) {
            f32x4 vh[8], vc[8];
            #pragma unroll
            for (int i = 0; i < 8; ++i) vh[i] = ld_sc0_16(hs + (i * 512 + tid) * 8);
            #pragma unroll
            for (int i = 0; i < 8; ++i) vc[i] = ld_sc0_16(cs + (i * 512 + tid) * 8);
            asm volatile("s_waitcnt vmcnt(0)" ::: "memory");
            #pragma unroll
            for (int i = 0; i < 8; ++i) {
                int ch = i * 512 + tid;
                int row = ch >> 6, q = ch & 63;
                unsigned o = row * 512 + ((q ^ (row & 7)) * 8);
                *reinterpret_cast<f32x4*>(sh_h + o) = vh[i];
                *reinterpret_cast<f32x4*>(sh_c + o) = vc[i];
            }
        } else {
            u64 v[32];
            #pragma unroll
            for (int i = 0; i < 8; ++i) {
                v[2 * i]      = ld_agent_u64(hs + (i * 512 + tid) * 8);
                v[2 * i + 1]  = ld_agent_u64(hs + (i * 512 + tid) * 8 + 4);
                v[16 + 2 * i] = ld_agent_u64(cs + (i * 512 + tid) * 8);
                v[17 + 2 * i] = ld_agent_u64(cs + (i * 512 + tid) * 8 + 4);
            }
            #pragma unroll
            for (int i = 0; i < 8; ++i) {
                int ch = i * 512 + tid;
                int row = ch >> 6, q = ch & 63;
                unsigned o = row * 512 + ((q ^ (row & 7)) * 8);
                *reinterpret_cast<u64*>(sh_h + o) = v[2 * i];
                *reinterpret_cast<u64*>(sh_h + o + 4) = v[2 * i + 1];
                *reinterpret_cast<u64*>(sh_c + o) = v[16 + 2 * i];
                *reinterpret_cast<u64*>(sh_c + o + 4) = v[17 + 2 * i];
            }
        }
    };

    // ---- encoder wave->tile mapping: wave wid owns gate tile wid; waves 0,1 own cs1 ----
    const int we = wid;                                         // 0..7
    const int colG = (we >> 1) * 512 + j0 + (we & 1) * 16 + l15;
    const u16* bpG = Wall + (size_t)colG * 512 + l4 * 8;
    const int colC = j0 + we * 16 + l15;                        // valid for we<2
    const u16* bpC = Wd + (size_t)colC * 512 + l4 * 8;
    const float bdC = (we < 2) ? bd[colC] : 0.f;

    // ---- PRELOAD t-invariant weight fragments into registers (once) ----
    bf16x8 wG[16], wC[16];
    #pragma unroll
    for (int kc = 0; kc < 16; ++kc)
        wG[kc] = *reinterpret_cast<const bf16x8*>(bpG + kc * 32);
    if (we < 2) {
        #pragma unroll
        for (int kc = 0; kc < 16; ++kc)
            wC[kc] = *reinterpret_cast<const bf16x8*>(bpC + kc * 32);
    }

    // XU register prefetch (non-temporal: read-once stream, keep out of L2)
    u16 xur[4][4];
    auto prefXU = [&](int t) {
        if (t < T_) {
            #pragma unroll
            for (int mm = 0; mm < 4; ++mm) {
                const u16* base = XU + ((size_t)t * B_ + r0 + mm * 16 + l4 * 4) * G_ + colG;
                #pragma unroll
                for (int v = 0; v < 4; ++v)
                    xur[mm][v] = __builtin_nontemporal_load(base + (size_t)v * G_);
            }
        }
    };
    prefXU(0);

    // ================= encoder: 75 steps =================
    int p = 0;
    for (int t = 0; t < T_; ++t) {
        stage(hb_[p], cb_[p]);
        __syncthreads();

        f32x4 acc[4] = {};
        f32x4 accC[4] = {};
        float ssqm[4] = {0.f, 0.f, 0.f, 0.f};
        #pragma unroll
        for (int kc = 0; kc < 16; ++kc) {
            unsigned ko = (unsigned)(((kc * 4 + l4) ^ (l15 & 7)) * 8);
            bf16x8 ah[4];
            #pragma unroll
            for (int mm = 0; mm < 4; ++mm)
                ah[mm] = *reinterpret_cast<const bf16x8*>(sh_h + (mm * 16 + l15) * 512 + ko);
            if (we == 2) {
                #pragma unroll
                for (int mm = 0; mm < 4; ++mm)
                    #pragma unroll
                    for (int e = 0; e < 8; ++e) {
                        float x = (float)ah[mm][e]; ssqm[mm] = fmaf(x, x, ssqm[mm]);
                    }
            }
            #pragma unroll
            for (int mm = 0; mm < 4; ++mm)
                acc[mm] = __builtin_amdgcn_mfma_f32_16x16x32_bf16(ah[mm], wG[kc], acc[mm], 0, 0, 0);
            if (we < 2) {
                bf16x8 ac[4];
                #pragma unroll
                for (int mm = 0; mm < 4; ++mm)
                    ac[mm] = *reinterpret_cast<const bf16x8*>(sh_c + (mm * 16 + l15) * 512 + ko);
                if (we == 0) {
                    #pragma unroll
                    for (int mm = 0; mm < 4; ++mm)
                        #pragma unroll
                        for (int e = 0; e < 8; ++e) {
                            float x = (float)ac[mm][e]; ssqm[mm] = fmaf(x, x, ssqm[mm]);
                        }
                }
                #pragma unroll
                for (int mm = 0; mm < 4; ++mm)
                    accC[mm] = __builtin_amdgcn_mfma_f32_16x16x32_bf16(ac[mm], wC[kc], accC[mm], 0, 0, 0);
            }
        }
        // row-norm scales: wave 2 -> shs (h), wave 0 -> scs (c)
        if (we == 0 || we == 2) {
            #pragma unroll
            for (int mm = 0; mm < 4; ++mm) {
                float s = ssqm[mm];
                s += __shfl_xor(s, 16);
                s += __shfl_xor(s, 32);
                if (l4 == 0) {
                    float sv = tangentize_scale(sqrtf(s));
                    if (we == 2) shs[mm * 16 + l15] = sv; else scs[mm * 16 + l15] = sv;
                }
            }
        }
        __syncthreads();

        // epilogue -> LDS
        {
            const int gcol = (we >> 1) * 32 + (we & 1) * 16 + l15;
            #pragma unroll
            for (int mm = 0; mm < 4; ++mm) {
                #pragma unroll
                for (int v = 0; v < 4; ++v) {
                    int lr = mm * 16 + l4 * 4 + v;
                    float val = acc[mm][v] * shs[lr] + bf2f(xur[mm][v]);
                    gt[lr * GTP + gcol] = f2bf(sigmoidf_(val));
                }
            }
            if (we < 2) {
                #pragma unroll
                for (int mm = 0; mm < 4; ++mm)
                    #pragma unroll
                    for (int v = 0; v < 4; ++v) {
                        int lr = mm * 16 + l4 * 4 + v;
                        float val = accC[mm][v] * scs[lr] + bdC;
                        csd[lr * CSP + we * 16 + l15] = f2bf(tanhf(val));
                    }
            }
        }
        __syncthreads();
        // pointwise
        {
            float scr = scs[prow];
            float ts = tf_g[(size_t)(r0 + prow) * T_ + t];
            u16x4 f4 = *reinterpret_cast<const u16x4*>(&gt[prow * GTP + 0 + pe0]);
            u16x4 i4 = *reinterpret_cast<const u16x4*>(&gt[prow * GTP + 32 + pe0]);
            u16x4 o4 = *reinterpret_cast<const u16x4*>(&gt[prow * GTP + 64 + pe0]);
            u16x4 m4 = *reinterpret_cast<const u16x4*>(&gt[prow * GTP + 96 + pe0]);
            u16x4 c14 = *reinterpret_cast<const u16x4*>(&csd[prow * CSP + pe0]);
            int cj = j0 + pe0;
            u16x4 cr4 = *reinterpret_cast<const u16x4*>(
                sh_c + prow * 512 + (((cj >> 3) ^ (prow & 7)) * 8) + (cj & 7));
            u16x4 hw, cw;
            float s2h = 0.f, s2c = 0.f;
            #pragma unroll
            for (int e = 0; e < 4; ++e) {
                float f = bf2f(f4[e]), ii = bf2f(i4[e]), o = bf2f(o4[e]), cm = bf2f(m4[e]);
                float c1 = bf2f(c14[e]);
                float ctv = scr * bf2f(cr4[e]);
                float cadj = ctv - c1 + c1 * ts;
                float cn = f * cadj + ii * cm;
                float hn = o * tanhf(cn);
                s2c += cn * cn; s2h += hn * hn;
                cw[e] = f2bf(cn); hw[e] = f2bf(hn);
            }
            size_t sidx = (size_t)(r0 + prow) * 512 + j0 + pe0;
            if (fastv) {
                *reinterpret_cast<u64*>(hb_[p ^ 1] + sidx) = __builtin_bit_cast(u64, hw);
                *reinterpret_cast<u64*>(cb_[p ^ 1] + sidx) = __builtin_bit_cast(u64, cw);
            } else {
                st_agent_u64(hb_[p ^ 1] + sidx, __builtin_bit_cast(u64, hw));
                st_agent_u64(cb_[p ^ 1] + sidx, __builtin_bit_cast(u64, cw));
            }
            if (t == T_ - 1) {
                #pragma unroll
                for (int off = 1; off < 8; off <<= 1) {
                    s2h += __shfl_xor(s2h, off); s2c += __shfl_xor(s2c, off);
                }
                if ((lane & 7) == 0) {
                    float* slot = pn + (size_t)(bt * 16 + ct) * 128;
                    if (fastv) { slot[prow] = s2h; slot[64 + prow] = s2c; }
                    else { st_agent_f32(&slot[prow], s2h); st_agent_f32(&slot[64 + prow], s2c); }
                }
            }
        }
        gsig();
        prefXU(t + 1);   // nt loads in flight during poll
        gwait();
        p ^= 1;
    }

    // ================= transition: hx = proj(tangent h), cx likewise =================
    {
        if (tid < 128) {
            const float* ps = pn + (size_t)bt * 2048 + tid;
            float s = 0.f;
            #pragma unroll
            for (int c2 = 0; c2 < 16; ++c2) s += ld_agent_f32(ps + c2 * 128);
            float n = sqrtf(s);
            float tsc = tangentize_scale(n);
            float tn = tsc * n;
            float S = tsc * (tn > MAXN ? MAXN / tn : 1.f);
            if (tid < 64) shs[tid] = S; else scs[tid - 64] = S;
        }
        __syncthreads();
        size_t sidx = (size_t)(r0 + prow) * 512 + j0 + pe0;
        u16x4 h4 = ld_state8(hb_[p] + sidx);
        u16x4 c4 = ld_state8(cb_[p] + sidx);
        u16x4 hw, cw;
        float Sh = shs[prow], Sc = scs[prow];
        #pragma unroll
        for (int e = 0; e < 4; ++e) {
            hw[e] = f2bf(Sh * bf2f(h4[e]));
            cw[e] = f2bf(Sc * bf2f(c4[e]));
        }
        st_agent_u64(hb_[0] + sidx, __builtin_bit_cast(u64, hw));
        st_agent_u64(cb_[0] + sidx, __builtin_bit_cast(u64, cw));
    }
    gsig(); gwait();

    // span softmax (ct==0 blocks)
    if (ct == 0 && tid < 256) {
        int row = tid >> 2, cl = tid & 3;
        float sum = 0.f;
        const u16* hx = hb_[0] + (size_t)(r0 + row) * 512;
        for (int k = 0; k < 512; k += 4) {
            u16x4 v = ld_state8(hx + k);
            #pragma unroll
            for (int e = 0; e < 4; ++e) sum += bf2f(v[e]) * Wspan[cl * 512 + k + e];
        }
        sum += bspan[cl];
        float mx = sum;
        mx = fmaxf(mx, __shfl_xor(mx, 1));
        mx = fmaxf(mx, __shfl_xor(mx, 2));
        float ex = expf(sum - mx);
        float den = ex + __shfl_xor(ex, 1);
        den += __shfl_xor(den, 2);
        out[(size_t)(r0 + row) * 4 + cl] = ex / den;
    }

    // ---- hoisted decoder pointers (proven path, unchanged) ----
    const int arow = r0 + m * 16 + l15;
    int colD[4];
    const u16* bpI[4];
    const u16* bpH[4];
    float bbD[4];
    #pragma unroll
    for (int i = 0; i < 4; ++i) {
        int q = nh * 4 + i;
        colD[i] = (q >> 1) * 512 + j0 + (q & 1) * 16 + l15;   // torch order i,f,g,o
        bpI[i] = Wih + (size_t)colD[i] * IN_ + l4 * 8;
        bpH[i] = Whh + (size_t)colD[i] * 512 + l4 * 8;
        bbD[i] = b_ih[colD[i]] + b_hh[colD[i]];
    }
    int colF[3];
    const u16* bpF[3];
    float bbF[3];
    const int nf = nh ? 1 : 2;
    #pragma unroll
    for (int i = 0; i < 3; ++i) {
        int q = nh * 2 + i;
        colF[i] = ct * 48 + q * 16 + l15;
        bpF[i] = Wfcin + (size_t)colF[i] * 512 + l4 * 8;
        bbF[i] = b_fcin[colF[i]];
    }

    // ================= decoder: 10 steps (sc1 state path, proven) =================
    int pd = 0;
    for (int s = 0; s < 10; ++s) {
        const u16* apI = ib_[pd] + (size_t)arow * IN_ + l4 * 8;
        const u16* apH = hb_[pd] + (size_t)arow * 512 + l4 * 8;

        f32x4 dacc[4] = {};
        #pragma unroll 4
        for (int kc = 0; kc < 24; ++kc) {
            bf16x8 a = ld_state16(apI + kc * 32);
            #pragma unroll
            for (int i = 0; i < 4; ++i) {
                bf16x8 b = *reinterpret_cast<const bf16x8*>(bpI[i] + kc * 32);
                dacc[i] = __builtin_amdgcn_mfma_f32_16x16x32_bf16(a, b, dacc[i], 0, 0, 0);
            }
        }
        #pragma unroll 4
        for (int kc = 0; kc < 16; ++kc) {
            bf16x8 a = ld_state16(apH + kc * 32);
            #pragma unroll
            for (int i = 0; i < 4; ++i) {
                bf16x8 b = *reinterpret_cast<const bf16x8*>(bpH[i] + kc * 32);
                dacc[i] = __builtin_amdgcn_mfma_f32_16x16x32_bf16(a, b, dacc[i], 0, 0, 0);
            }
        }
        #pragma unroll
        for (int i = 0; i < 4; ++i) {
            int q = nh * 4 + i;
            #pragma unroll
            for (int v = 0; v < 4; ++v) {
                int lr = m * 16 + l4 * 4 + v;
                gt[lr * GTP + (q >> 1) * 32 + (q & 1) * 16 + l15] = f2bf(dacc[i][v] + bbD[i]);
            }
        }
        __syncthreads();
        {
            u16x4 i4 = *reinterpret_cast<const u16x4*>(&gt[prow * GTP + 0 + pe0]);
            u16x4 f4 = *reinterpret_cast<const u16x4*>(&gt[prow * GTP + 32 + pe0]);
            u16x4 g4 = *reinterpret_cast<const u16x4*>(&gt[prow * GTP + 64 + pe0]);
            u16x4 o4 = *reinterpret_cast<const u16x4*>(&gt[prow * GTP + 96 + pe0]);
            size_t sidx = (size_t)(r0 + prow) * 512 + j0 + pe0;
            u16x4 cr4 = ld_state8(cb_[pd] + sidx);
            u16x4 hw, cw;
            #pragma unroll
            for (int e = 0; e < 4; ++e) {
                float ii = sigmoidf_(bf2f(i4[e]));
                float ff = sigmoidf_(bf2f(f4[e]));
                float gg = tanhf(bf2f(g4[e]));
                float oo = sigmoidf_(bf2f(o4[e]));
                float cn = ff * bf2f(cr4[e]) + ii * gg;
                float hn = oo * tanhf(cn);
                cw[e] = f2bf(cn); hw[e] = f2bf(hn);
            }
            st_agent_u64(hb_[pd ^ 1] + sidx, __builtin_bit_cast(u64, hw));
            st_agent_u64(cb_[pd ^ 1] + sidx, __builtin_bit_cast(u64, cw));
        }
        gsig(); gwait();

        const u16* hp2 = hb_[pd ^ 1];
        if (s < 9) {
            const u16* ap2 = hp2 + (size_t)arow * 512 + l4 * 8;
            f32x4 facc[3] = {};
            #pragma unroll 4
            for (int kc = 0; kc < 16; ++kc) {
                bf16x8 a = ld_state16(ap2 + kc * 32);
                for (int i = 0; i < nf; ++i) {
                    bf16x8 b = *reinterpret_cast<const bf16x8*>(bpF[i] + kc * 32);
                    facc[i] = __builtin_amdgcn_mfma_f32_16x16x32_bf16(a, b, facc[i], 0, 0, 0);
                }
            }
            for (int i = 0; i < nf; ++i) {
                #pragma unroll
                for (int v = 0; v < 4; ++v) {
                    int lr = m * 16 + l4 * 4 + v;
                    st_agent_u16(ib_[pd ^ 1] + (size_t)(r0 + lr) * IN_ + colF[i],
                                 f2bf(fmaxf(facc[i][v] + bbF[i], 0.f)));
                }
            }
        }
        if (ct == 15 && tid < 128) {
            int row = tid >> 1, cl = tid & 1;
            const u16* hx = hp2 + (size_t)(r0 + row) * 512;
            float sum = 0.f;
            for (int k = 0; k < 512; k += 4) {
                u16x4 v = ld_state8(hx + k);
                #pragma unroll
                for (int e = 0; e < 4; ++e) sum += bf2f(v[e]) * Wfco[cl * 512 + k + e];
            }
            sum += b_fco[cl];
            float o2 = __shfl_xor(sum, 1);
            float mx = fmaxf(sum, o2);
            float ex = expf(sum - mx), eo = expf(o2 - mx);
            out[4096 + (size_t)(r0 + row) * 20 + s * 2 + cl] = ex / (ex + eo);
        }
        if (s < 9) { gsig(); gwait(); }
        pd ^= 1;
    }
}

// ---------------- launch ----------------

extern "C" void kernel_launch(void* const* d_in, const int* in_sizes, int n_in,
                              void* d_out, int out_size, void* d_ws, size_t ws_size,
                              hipStream_t stream) {
    (void)in_sizes; (void)n_in; (void)out_size;
    const float* sent    = (const float*)d_in[0];
    const float* timef   = (const float*)d_in[1];
    const float* Wd      = (const float*)d_in[2];
    const float* bd      = (const float*)d_in[3];
    const float* W_all   = (const float*)d_in[4];
    const float* b_all   = (const float*)d_in[5];
    const float* U_all   = (const float*)d_in[6];
    const float* b_U     = (const float*)d_in[7];
    const float* W_ih    = (const float*)d_in[8];
    const float* b_ih    = (const float*)d_in[9];
    const float* W_hh    = (const float*)d_in[10];
    const float* b_hh    = (const float*)d_in[11];
    const float* W_fc_in = (const float*)d_in[12];
    const float* b_fc_in = (const float*)d_in[13];
    const float* W_fc_out= (const float*)d_in[14];
    const float* b_fc_out= (const float*)d_in[15];
    const float* W_span  = (const float*)d_in[16];
    const float* b_span  = (const float*)d_in[17];
    float* out = (float*)d_out;

    char* ws = (char*)d_ws;
    size_t off = 0;
    auto alloc = [&](size_t bytes) -> void* {
        void* p = ws + off; off = (off + bytes + 255) & ~(size_t)255; return p;
    };
    float* tf     = (float*)alloc((size_t)B_ * T_ * 4);
    u16* Wall_b   = (u16*)alloc((size_t)G_ * H_ * 2);
    u16* Uall_b   = (u16*)alloc((size_t)G_ * IN_ * 2);
    u16* Wd_b     = (u16*)alloc((size_t)H_ * H_ * 2);
    u16* Wih_b    = (u16*)alloc((size_t)G_ * IN_ * 2);
    u16* Whh_b    = (u16*)alloc((size_t)G_ * H_ * 2);
    u16* Wfcin_b  = (u16*)alloc((size_t)IN_ * H_ * 2);
    float* xscale = (float*)alloc((size_t)B_ * T_ * 4);
    u16* hbuf0    = (u16*)alloc((size_t)B_ * H_ * 2);
    u16* hbuf1    = (u16*)alloc((size_t)B_ * H_ * 2);
    u16* cbuf0    = (u16*)alloc((size_t)B_ * H_ * 2);
    u16* cbuf1    = (u16*)alloc((size_t)B_ * H_ * 2);
    u16* ibuf0    = (u16*)alloc((size_t)B_ * IN_ * 2);
    u16* ibuf1    = (u16*)alloc((size_t)B_ * IN_ * 2);
    float* pn     = (float*)alloc((size_t)16 * 16 * 128 * 4);
    unsigned* flags  = (unsigned*)alloc(16 * 16 * 4);
    unsigned* flagsF = (unsigned*)alloc(16 * 16 * 4);
    unsigned* xcds   = (unsigned*)alloc(256 * 4);
    u16* XU       = (u16*)alloc((size_t)B_ * T_ * G_ * 2);
    u16* sentb    = (u16*)alloc((size_t)B_ * T_ * IN_ * 2);
    bool pathA = (off <= ws_size);

    // per-launch (= per-replay) re-init
    hipMemsetAsync(flags, 0, 16 * 16 * 4, stream);
    hipMemsetAsync(flagsF, 0, 16 * 16 * 4, stream);
    hipMemsetAsync(xcds, 0, 256 * 4, stream);
    hipMemsetAsync(pn, 0, (size_t)16 * 16 * 128 * 4, stream);
    hipMemsetAsync(hbuf0, 0, (size_t)B_ * H_ * 2, stream);
    hipMemsetAsync(cbuf0, 0, (size_t)B_ * H_ * 2, stream);
    hipMemsetAsync(ibuf0, 0, (size_t)B_ * IN_ * 2, stream);

    auto cvt = [&](const float* s, u16* d, int n) {
        cvt_f32_bf16<<<(n / 4 + 255) / 256, 256, 0, stream>>>(s, d, n);
    };
    cvt(W_all, Wall_b, G_ * H_);
    cvt(U_all, Uall_b, G_ * IN_);
    cvt(Wd, Wd_b, H_ * H_);
    cvt(W_ih, Wih_b, G_ * IN_);
    cvt(W_hh, Whh_b, G_ * H_);
    cvt(W_fc_in, Wfcin_b, IN_ * H_);

    tf_kernel<<<B_, 128, 0, stream>>>(timef, tf);

    if (pathA) {
        prep_sentb<<<B_ * T_, 256, 0, stream>>>(sent, sentb);
        xu_gemm<0><<<(B_ * T_ / 128) * (G_ / 128), 256, 0, stream>>>(
            sentb, nullptr, Uall_b, b_all, b_U, XU);
    } else {
        xscale_kernel<<<B_ * T_, 256, 0, stream>>>(sent, xscale);
        xu_gemm<1><<<(B_ * T_ / 128) * (G_ / 128), 256, 0, stream>>>(
            sent, xscale, Uall_b, b_all, b_U, XU);
    }

    persistent9<<<GRIDN, 512, 0, stream>>>(
        XU, tf, Wall_b, Wd_b, bd, Wih_b, Whh_b, b_ih, b_hh,
        Wfcin_b, b_fc_in, W_fc_out, b_fc_out, W_span, b_span,
        hbuf0, hbuf1, cbuf0, cbuf1, ibuf0, ibuf1,
        pn, flags, flagsF, xcds, out);
}

// Round 12
// 2156.503 us; speedup vs baseline: 1.4142x; 1.4142x over previous
//
#include <hip/hip_runtime.h>
#include <cmath>

#define B_ 1024
#define T_ 75
#define IN_ 768
#define H_ 512
#define G_ 2048
#define GRIDN 256

#define EPSF 1e-15f
#define MAXN 0.99999f
#define GTP 136          // padded gt row (u16)
#define CSP 36           // padded csd row (u16)

typedef __bf16 bf16_t;
typedef bf16_t bf16x8 __attribute__((ext_vector_type(8)));
typedef float f32x4 __attribute__((ext_vector_type(4)));
typedef unsigned short u16;
typedef u16 u16x8 __attribute__((ext_vector_type(8)));
typedef u16 u16x4 __attribute__((ext_vector_type(4)));
typedef unsigned long long u64;
typedef u64 u64x2 __attribute__((ext_vector_type(2)));

// ---------------- scalar helpers ----------------

__device__ inline float sigmoidf_(float x) { return 1.0f / (1.0f + expf(-x)); }

__device__ inline u16 f2bf(float f) {
    unsigned u = __builtin_bit_cast(unsigned, f);
    u = u + 0x7FFFu + ((u >> 16) & 1u);
    return (u16)(u >> 16);
}
__device__ inline float bf2f(u16 h) {
    return __builtin_bit_cast(float, (unsigned)h << 16);
}

__device__ inline float tangentize_scale(float n) {
    float n1 = fmaxf(n, EPSF);
    float m = fminf(tanhf(n1), MAXN);
    return atanhf(m) / n1;
}
__device__ inline float expproj_scale(float n) {
    float n1 = fmaxf(n, EPSF);
    return fminf(tanhf(n1), MAXN) / n1;
}

__device__ inline float blockReduceSum(float v) {
    __shared__ float sm[8];
    __syncthreads();
    #pragma unroll
    for (int off = 32; off > 0; off >>= 1) v += __shfl_down(v, off, 64);
    int w = threadIdx.x >> 6, lane = threadIdx.x & 63;
    if (lane == 0) sm[w] = v;
    __syncthreads();
    int nw = (blockDim.x + 63) >> 6;
    if (threadIdx.x == 0) {
        float r = sm[0];
        for (int i = 1; i < nw; ++i) r += sm[i];
        sm[0] = r;
    }
    __syncthreads();
    return sm[0];
}

// ---- agent-scope (sc1) accessors: proven cross-block path ----
__device__ inline void st_agent_u64(void* p, u64 v) {
    __hip_atomic_store((u64*)p, v, __ATOMIC_RELAXED, __HIP_MEMORY_SCOPE_AGENT);
}
__device__ inline void st_agent_u32(unsigned* p, unsigned v) {
    __hip_atomic_store(p, v, __ATOMIC_RELAXED, __HIP_MEMORY_SCOPE_AGENT);
}
__device__ inline void st_agent_f32(float* p, float v) {
    __hip_atomic_store(p, v, __ATOMIC_RELAXED, __HIP_MEMORY_SCOPE_AGENT);
}
__device__ inline void st_agent_u16(u16* p, u16 v) {
    __hip_atomic_store(p, v, __ATOMIC_RELAXED, __HIP_MEMORY_SCOPE_AGENT);
}
__device__ inline u64 ld_agent_u64(const void* p) {
    return __hip_atomic_load((const u64*)p, __ATOMIC_RELAXED, __HIP_MEMORY_SCOPE_AGENT);
}
__device__ inline unsigned ld_agent_u32(const unsigned* p) {
    return __hip_atomic_load(p, __ATOMIC_RELAXED, __HIP_MEMORY_SCOPE_AGENT);
}
__device__ inline float ld_agent_f32(const float* p) {
    return __hip_atomic_load(p, __ATOMIC_RELAXED, __HIP_MEMORY_SCOPE_AGENT);
}
__device__ inline bf16x8 ld_state16(const u16* p) {
    u64x2 t;
    t.x = ld_agent_u64(p);
    t.y = ld_agent_u64(p + 4);
    return __builtin_bit_cast(bf16x8, t);
}
__device__ inline u16x4 ld_state8(const u16* p) {
    return __builtin_bit_cast(u16x4, ld_agent_u64(p));
}

// sc0 16B load: bypasses L0/L1, reads the XCD-shared L2. Result NOT ready
// until a following s_waitcnt vmcnt(0) — caller drains.
__device__ inline f32x4 ld_sc0_16(const u16* p) {
    f32x4 r;
    asm volatile("global_load_dwordx4 %0, %1, off sc0" : "=v"(r) : "v"(p));
    return r;
}
__device__ inline bf16x8 ld_sc0_nb(const u16* p) {   // no waitcnt; caller drains
    f32x4 r;
    asm volatile("global_load_dwordx4 %0, %1, off sc0" : "=v"(r) : "v"(p));
    return __builtin_bit_cast(bf16x8, r);
}
__device__ inline void drain_vm() {                  // drain + scheduling fence (rule #18)
    asm volatile("s_waitcnt vmcnt(0)" ::: "memory");
    __builtin_amdgcn_sched_barrier(0);
}

// ---------------- precompute kernels ----------------

__global__ void cvt_f32_bf16(const float* __restrict__ s, u16* __restrict__ d, int n) {
    int i = (blockIdx.x * 256 + threadIdx.x) * 4;
    if (i < n) {
        float4 f = *reinterpret_cast<const float4*>(s + i);
        d[i + 0] = f2bf(f.x); d[i + 1] = f2bf(f.y);
        d[i + 2] = f2bf(f.z); d[i + 3] = f2bf(f.w);
    }
}

__global__ __launch_bounds__(256) void prep_sentb(const float* __restrict__ sent,
                                                  u16* __restrict__ sentb) {
    int bid = blockIdx.x;            // = b*75 + t
    int b = bid / T_, t = bid - b * T_;
    const float* src = sent + (size_t)bid * IN_;
    float v[3]; float ss = 0.f;
    #pragma unroll
    for (int e = 0; e < 3; ++e) { v[e] = src[threadIdx.x + e * 256]; ss += v[e] * v[e]; }
    float tot = blockReduceSum(ss);
    float sc = tangentize_scale(sqrtf(tot));
    u16* dst = sentb + ((size_t)t * B_ + b) * IN_;
    #pragma unroll
    for (int e = 0; e < 3; ++e) dst[threadIdx.x + e * 256] = f2bf(v[e] * sc);
}

__global__ __launch_bounds__(256) void xscale_kernel(const float* __restrict__ x,
                                                     float* __restrict__ xscale) {
    int row = blockIdx.x;
    const float* p = x + (size_t)row * IN_;
    float s = 0.f;
    for (int k = threadIdx.x; k < IN_; k += 256) { float v = p[k]; s += v * v; }
    float tot = blockReduceSum(s);
    if (threadIdx.x == 0) xscale[row] = tangentize_scale(sqrtf(tot));
}

__global__ void tf_kernel(const float* __restrict__ x, float* __restrict__ tf) {
    int b = blockIdx.x;
    float v = (threadIdx.x < T_) ? x[(size_t)b * T_ + threadIdx.x] : 0.f;
    float tot = blockReduceSum(v * v);
    float s = expproj_scale(sqrtf(tot));
    if (threadIdx.x < T_) tf[(size_t)b * T_ + threadIdx.x] = s * v;
}

// ---------------- XU GEMM (t-major) ----------------
template<int F32SRC>
__global__ __launch_bounds__(256) void xu_gemm(const void* __restrict__ Asrc,
    const float* __restrict__ xscale, const u16* __restrict__ W,
    const float* __restrict__ b1, const float* __restrict__ b2, u16* __restrict__ C)
{
    __shared__ __align__(16) unsigned char As[128 * 128];
    __shared__ __align__(16) unsigned char Ws[128 * 128];
    int bid = (int)blockIdx.x;
    bid = (bid & 7) * ((int)gridDim.x >> 3) + (bid >> 3);
    const int bn = (bid % 16) * 128;
    const int bm = (bid / 16) * 128;
    const int tq = bm >> 10;
    const int b0 = bm & 1023;

    const int tid = threadIdx.x;
    const int lane = tid & 63;
    const int wid = tid >> 6;
    const int wr = wid >> 1, wc = wid & 1;
    const int l15 = lane & 15, l4 = lane >> 4;

    f32x4 acc[4][4] = {};

    for (int k0 = 0; k0 < IN_; k0 += 64) {
        __syncthreads();
        #pragma unroll
        for (int c = 0; c < 4; ++c) {
            int ch = c * 256 + tid;
            int r = ch >> 3, q = ch & 7;
            unsigned off = (unsigned)(r * 128 + ((q ^ (r & 7)) * 16));
            if (F32SRC) {
                int b = b0 + r;
                const float* src = (const float*)Asrc + ((size_t)b * T_ + tq) * IN_ + k0 + q * 8;
                float rs = xscale[(size_t)b * T_ + tq];
                float4 f0 = *reinterpret_cast<const float4*>(src);
                float4 f1 = *reinterpret_cast<const float4*>(src + 4);
                u16x8 v;
                v[0] = f2bf(f0.x * rs); v[1] = f2bf(f0.y * rs);
                v[2] = f2bf(f0.z * rs); v[3] = f2bf(f0.w * rs);
                v[4] = f2bf(f1.x * rs); v[5] = f2bf(f1.y * rs);
                v[6] = f2bf(f1.z * rs); v[7] = f2bf(f1.w * rs);
                *reinterpret_cast<u16x8*>(As + off) = v;
            } else {
                const u16* src = (const u16*)Asrc + (size_t)(bm + r) * IN_ + k0 + q * 8;
                *reinterpret_cast<u16x8*>(As + off) = *reinterpret_cast<const u16x8*>(src);
            }
        }
        #pragma unroll
        for (int c = 0; c < 4; ++c) {
            int ch = c * 256 + tid;
            int r = ch >> 3, q = ch & 7;
            unsigned off = (unsigned)(r * 128 + ((q ^ (r & 7)) * 16));
            const u16* src = W + (size_t)(bn + r) * IN_ + k0 + q * 8;
            *reinterpret_cast<u16x8*>(Ws + off) = *reinterpret_cast<const u16x8*>(src);
        }
        __syncthreads();
        #pragma unroll
        for (int ks = 0; ks < 2; ++ks) {
            bf16x8 af[4], bf[4];
            #pragma unroll
            for (int m = 0; m < 4; ++m) {
                int r = wr * 64 + m * 16 + l15;
                af[m] = *reinterpret_cast<const bf16x8*>(As + r * 128 + (((ks * 4 + l4) ^ (r & 7)) * 16));
            }
            #pragma unroll
            for (int n = 0; n < 4; ++n) {
                int r = wc * 64 + n * 16 + l15;
                bf[n] = *reinterpret_cast<const bf16x8*>(Ws + r * 128 + (((ks * 4 + l4) ^ (r & 7)) * 16));
            }
            #pragma unroll
            for (int m = 0; m < 4; ++m)
                #pragma unroll
                for (int n = 0; n < 4; ++n)
                    acc[m][n] = __builtin_amdgcn_mfma_f32_16x16x32_bf16(af[m], bf[n], acc[m][n], 0, 0, 0);
        }
    }

    #pragma unroll
    for (int m = 0; m < 4; ++m)
        #pragma unroll
        for (int n = 0; n < 4; ++n) {
            int col = bn + wc * 64 + n * 16 + l15;
            float bb = b1[col] + b2[col];
            #pragma unroll
            for (int v = 0; v < 4; ++v) {
                int row = bm + wr * 64 + m * 16 + l4 * 4 + v;
                C[(size_t)row * G_ + col] = f2bf(acc[m][n][v] + bb);
            }
        }
}

// ---------------- persistent kernel: round-10 base + uncapped wG hoist + fast decoder ----

__global__ __launch_bounds__(512) void persistent10(
    const u16* __restrict__ XU, const float* __restrict__ tf_g,
    const u16* __restrict__ Wall, const u16* __restrict__ Wd, const float* __restrict__ bd,
    const u16* __restrict__ Wih, const u16* __restrict__ Whh,
    const float* __restrict__ b_ih, const float* __restrict__ b_hh,
    const u16* __restrict__ Wfcin, const float* __restrict__ b_fcin,
    const float* __restrict__ Wfco, const float* __restrict__ b_fco,
    const float* __restrict__ Wspan, const float* __restrict__ bspan,
    u16* __restrict__ hb0, u16* __restrict__ hb1,
    u16* __restrict__ cb0, u16* __restrict__ cb1,
    u16* __restrict__ ib0, u16* __restrict__ ib1,
    float* __restrict__ pn,
    unsigned* __restrict__ flags,     // sc1 / LLC
    unsigned* __restrict__ flagsF,    // plain / L2
    unsigned* __restrict__ xcds,
    float* __restrict__ out)
{
    const int bid = (int)blockIdx.x;
    const int bt = bid & 15, ct = bid >> 4;
    const int r0 = bt * 64, j0 = ct * 32;
    const int tid = threadIdx.x;
    const int lane = tid & 63;
    const int wid = tid >> 6;
    const int m = wid & 3, nh = wid >> 2;   // decoder mapping
    const int l15 = lane & 15, l4 = lane >> 4;

    u16* hb_[2] = {hb0, hb1};
    u16* cb_[2] = {cb0, cb1};
    u16* ib_[2] = {ib0, ib1};

    __shared__ u16 sh_h[64 * 512];
    __shared__ u16 sh_c[64 * 512];
    __shared__ u16 gt[64 * GTP];
    __shared__ u16 csd[64 * CSP];
    __shared__ float shs[64], scs[64];
    __shared__ int fastF;

    const int prow = tid >> 3, pe0 = (tid & 7) * 4;

    unsigned epoch = 0;
    unsigned* gflag = flags + bt * 16;
    unsigned* fflag = flagsF + bt * 16;
    bool fastv = false;

    auto gsig = [&]() {
        asm volatile("s_waitcnt vmcnt(0)" ::: "memory");
        __syncthreads();
        ++epoch;
        if (tid == 0) {
            if (fastv) *(volatile unsigned*)(fflag + ct) = epoch;
            st_agent_u32(&gflag[ct], epoch);
        }
    };
    auto gwait = [&]() {
        if (tid < 16) {
            if (fastv) {
                unsigned it = 0, v;
                for (;;) {
                    asm volatile("global_load_dword %0, %1, off sc0\n\ts_waitcnt vmcnt(0)"
                                 : "=v"(v) : "v"(fflag + tid) : "memory");
                    if (v >= epoch) break;
                    if ((it++ & 7) == 7 && ld_agent_u32(&gflag[tid]) >= epoch) break;
                    __builtin_amdgcn_s_sleep(1);
                }
            } else {
                while (ld_agent_u32(&gflag[tid]) < epoch) __builtin_amdgcn_s_sleep(1);
            }
        }
        __syncthreads();
    };

    // ---- XCD co-residency detection ----
    {
        unsigned xcd = __builtin_amdgcn_s_getreg(6164);
        if (tid == 0) st_agent_u32(&xcds[bid], 0x100u | (xcd & 0xFu));
        gsig(); gwait();
        if (tid < 16) {
            unsigned mine = ld_agent_u32(&xcds[(tid << 4) + bt]);
            unsigned ref  = ld_agent_u32(&xcds[bt]);
            u64 b = __ballot(mine == ref);
            if (tid == 0) fastF = ((b & 0xFFFFull) == 0xFFFFull) ? 1 : 0;
        }
        __syncthreads();
        fastv = (fastF != 0);
    }

    // ---- staging of h+c into LDS (XOR-swizzled), single drain ----
    auto stage = [&](const u16* hsrc, const u16* csrc) {
        const u16* hs = hsrc + (size_t)r0 * 512;
        const u16* cs = csrc + (size_t)r0 * 512;
        if (fastv) {
            f32x4 vh[8], vc[8];
            #pragma unroll
            for (int i = 0; i < 8; ++i) vh[i] = ld_sc0_16(hs + (i * 512 + tid) * 8);
            #pragma unroll
            for (int i = 0; i < 8; ++i) vc[i] = ld_sc0_16(cs + (i * 512 + tid) * 8);
            asm volatile("s_waitcnt vmcnt(0)" ::: "memory");
            #pragma unroll
            for (int i = 0; i < 8; ++i) {
                int ch = i * 512 + tid;
                int row = ch >> 6, q = ch & 63;
                unsigned o = row * 512 + ((q ^ (row & 7)) * 8);
                *reinterpret_cast<f32x4*>(sh_h + o) = vh[i];
                *reinterpret_cast<f32x4*>(sh_c + o) = vc[i];
            }
        } else {
            u64 v[32];
            #pragma unroll
            for (int i = 0; i < 8; ++i) {
                v[2 * i]      = ld_agent_u64(hs + (i * 512 + tid) * 8);
                v[2 * i + 1]  = ld_agent_u64(hs + (i * 512 + tid) * 8 + 4);
                v[16 + 2 * i] = ld_agent_u64(cs + (i * 512 + tid) * 8);
                v[17 + 2 * i] = ld_agent_u64(cs + (i * 512 + tid) * 8 + 4);
            }
            #pragma unroll
            for (int i = 0; i < 8; ++i) {
                int ch = i * 512 + tid;
                int row = ch >> 6, q = ch & 63;
                unsigned o = row * 512 + ((q ^ (row & 7)) * 8);
                *reinterpret_cast<u64*>(sh_h + o) = v[2 * i];
                *reinterpret_cast<u64*>(sh_h + o + 4) = v[2 * i + 1];
                *reinterpret_cast<u64*>(sh_c + o) = v[16 + 2 * i];
                *reinterpret_cast<u64*>(sh_c + o + 4) = v[17 + 2 * i];
            }
        }
    };

    // ---- encoder wave->tile mapping ----
    const int we = wid;
    const int colG = (we >> 1) * 512 + j0 + (we & 1) * 16 + l15;
    const u16* bpG = Wall + (size_t)colG * 512 + l4 * 8;
    const int colC = j0 + we * 16 + l15;
    const u16* bpC = Wd + (size_t)colC * 512 + l4 * 8;
    const float bdC = (we < 2) ? bd[colC] : 0.f;

    // ---- wG hoist: 64 VGPRs of t-invariant gate weights (uncapped regalloc) ----
    bf16x8 wG[16];
    #pragma unroll
    for (int kc = 0; kc < 16; ++kc)
        wG[kc] = *reinterpret_cast<const bf16x8*>(bpG + kc * 32);

    u16 xur[4][4];
    auto prefXU = [&](int t) {
        if (t < T_) {
            #pragma unroll
            for (int mm = 0; mm < 4; ++mm) {
                const u16* base = XU + ((size_t)t * B_ + r0 + mm * 16 + l4 * 4) * G_ + colG;
                #pragma unroll
                for (int v = 0; v < 4; ++v)
                    xur[mm][v] = __builtin_nontemporal_load(base + (size_t)v * G_);
            }
        }
    };
    prefXU(0);

    // ================= encoder: 75 steps =================
    int p = 0;
    for (int t = 0; t < T_; ++t) {
        stage(hb_[p], cb_[p]);
        __syncthreads();

        f32x4 acc[4] = {};
        f32x4 accC[4] = {};
        float ssqm[4] = {0.f, 0.f, 0.f, 0.f};
        #pragma unroll
        for (int kc = 0; kc < 16; ++kc) {
            unsigned ko = (unsigned)(((kc * 4 + l4) ^ (l15 & 7)) * 8);
            bf16x8 ah[4];
            #pragma unroll
            for (int mm = 0; mm < 4; ++mm)
                ah[mm] = *reinterpret_cast<const bf16x8*>(sh_h + (mm * 16 + l15) * 512 + ko);
            if (we == 2) {
                #pragma unroll
                for (int mm = 0; mm < 4; ++mm)
                    #pragma unroll
                    for (int e = 0; e < 8; ++e) {
                        float x = (float)ah[mm][e]; ssqm[mm] = fmaf(x, x, ssqm[mm]);
                    }
            }
            #pragma unroll
            for (int mm = 0; mm < 4; ++mm)
                acc[mm] = __builtin_amdgcn_mfma_f32_16x16x32_bf16(ah[mm], wG[kc], acc[mm], 0, 0, 0);
            if (we < 2) {
                bf16x8 bC = *reinterpret_cast<const bf16x8*>(bpC + kc * 32);
                bf16x8 ac[4];
                #pragma unroll
                for (int mm = 0; mm < 4; ++mm)
                    ac[mm] = *reinterpret_cast<const bf16x8*>(sh_c + (mm * 16 + l15) * 512 + ko);
                if (we == 0) {
                    #pragma unroll
                    for (int mm = 0; mm < 4; ++mm)
                        #pragma unroll
                        for (int e = 0; e < 8; ++e) {
                            float x = (float)ac[mm][e]; ssqm[mm] = fmaf(x, x, ssqm[mm]);
                        }
                }
                #pragma unroll
                for (int mm = 0; mm < 4; ++mm)
                    accC[mm] = __builtin_amdgcn_mfma_f32_16x16x32_bf16(ac[mm], bC, accC[mm], 0, 0, 0);
            }
        }
        if (we == 0 || we == 2) {
            #pragma unroll
            for (int mm = 0; mm < 4; ++mm) {
                float s = ssqm[mm];
                s += __shfl_xor(s, 16);
                s += __shfl_xor(s, 32);
                if (l4 == 0) {
                    float sv = tangentize_scale(sqrtf(s));
                    if (we == 2) shs[mm * 16 + l15] = sv; else scs[mm * 16 + l15] = sv;
                }
            }
        }
        __syncthreads();

        // epilogue -> LDS
        {
            const int gcol = (we >> 1) * 32 + (we & 1) * 16 + l15;
            #pragma unroll
            for (int mm = 0; mm < 4; ++mm) {
                #pragma unroll
                for (int v = 0; v < 4; ++v) {
                    int lr = mm * 16 + l4 * 4 + v;
                    float val = acc[mm][v] * shs[lr] + bf2f(xur[mm][v]);
                    gt[lr * GTP + gcol] = f2bf(sigmoidf_(val));
                }
            }
            if (we < 2) {
                #pragma unroll
                for (int mm = 0; mm < 4; ++mm)
                    #pragma unroll
                    for (int v = 0; v < 4; ++v) {
                        int lr = mm * 16 + l4 * 4 + v;
                        float val = accC[mm][v] * scs[lr] + bdC;
                        csd[lr * CSP + we * 16 + l15] = f2bf(tanhf(val));
                    }
            }
        }
        __syncthreads();
        // pointwise
        {
            float scr = scs[prow];
            float ts = tf_g[(size_t)(r0 + prow) * T_ + t];
            u16x4 f4 = *reinterpret_cast<const u16x4*>(&gt[prow * GTP + 0 + pe0]);
            u16x4 i4 = *reinterpret_cast<const u16x4*>(&gt[prow * GTP + 32 + pe0]);
            u16x4 o4 = *reinterpret_cast<const u16x4*>(&gt[prow * GTP + 64 + pe0]);
            u16x4 m4 = *reinterpret_cast<const u16x4*>(&gt[prow * GTP + 96 + pe0]);
            u16x4 c14 = *reinterpret_cast<const u16x4*>(&csd[prow * CSP + pe0]);
            int cj = j0 + pe0;
            u16x4 cr4 = *reinterpret_cast<const u16x4*>(
                sh_c + prow * 512 + (((cj >> 3) ^ (prow & 7)) * 8) + (cj & 7));
            u16x4 hw, cw;
            float s2h = 0.f, s2c = 0.f;
            #pragma unroll
            for (int e = 0; e < 4; ++e) {
                float f = bf2f(f4[e]), ii = bf2f(i4[e]), o = bf2f(o4[e]), cm = bf2f(m4[e]);
                float c1 = bf2f(c14[e]);
                float ctv = scr * bf2f(cr4[e]);
                float cadj = ctv - c1 + c1 * ts;
                float cn = f * cadj + ii * cm;
                float hn = o * tanhf(cn);
                s2c += cn * cn; s2h += hn * hn;
                cw[e] = f2bf(cn); hw[e] = f2bf(hn);
            }
            size_t sidx = (size_t)(r0 + prow) * 512 + j0 + pe0;
            if (fastv) {
                *reinterpret_cast<u64*>(hb_[p ^ 1] + sidx) = __builtin_bit_cast(u64, hw);
                *reinterpret_cast<u64*>(cb_[p ^ 1] + sidx) = __builtin_bit_cast(u64, cw);
            } else {
                st_agent_u64(hb_[p ^ 1] + sidx, __builtin_bit_cast(u64, hw));
                st_agent_u64(cb_[p ^ 1] + sidx, __builtin_bit_cast(u64, cw));
            }
            if (t == T_ - 1) {
                #pragma unroll
                for (int off = 1; off < 8; off <<= 1) {
                    s2h += __shfl_xor(s2h, off); s2c += __shfl_xor(s2c, off);
                }
                if ((lane & 7) == 0) {
                    float* slot = pn + (size_t)(bt * 16 + ct) * 128;
                    if (fastv) { slot[prow] = s2h; slot[64 + prow] = s2c; }
                    else { st_agent_f32(&slot[prow], s2h); st_agent_f32(&slot[64 + prow], s2c); }
                }
            }
        }
        gsig();
        prefXU(t + 1);
        gwait();
        p ^= 1;
    }

    // ================= transition =================
    {
        if (tid < 128) {
            const float* ps = pn + (size_t)bt * 2048 + tid;
            float s = 0.f;
            #pragma unroll
            for (int c2 = 0; c2 < 16; ++c2) s += ld_agent_f32(ps + c2 * 128);
            float n = sqrtf(s);
            float tsc = tangentize_scale(n);
            float tn = tsc * n;
            float S = tsc * (tn > MAXN ? MAXN / tn : 1.f);
            if (tid < 64) shs[tid] = S; else scs[tid - 64] = S;
        }
        __syncthreads();
        size_t sidx = (size_t)(r0 + prow) * 512 + j0 + pe0;
        u16x4 h4 = ld_state8(hb_[p] + sidx);
        u16x4 c4 = ld_state8(cb_[p] + sidx);
        u16x4 hw, cw;
        float Sh = shs[prow], Sc = scs[prow];
        #pragma unroll
        for (int e = 0; e < 4; ++e) {
            hw[e] = f2bf(Sh * bf2f(h4[e]));
            cw[e] = f2bf(Sc * bf2f(c4[e]));
        }
        st_agent_u64(hb_[0] + sidx, __builtin_bit_cast(u64, hw));
        st_agent_u64(cb_[0] + sidx, __builtin_bit_cast(u64, cw));
    }
    gsig(); gwait();

    // span softmax (ct==0 blocks)
    if (ct == 0 && tid < 256) {
        int row = tid >> 2, cl = tid & 3;
        float sum = 0.f;
        const u16* hx = hb_[0] + (size_t)(r0 + row) * 512;
        for (int k = 0; k < 512; k += 4) {
            u16x4 v = ld_state8(hx + k);
            #pragma unroll
            for (int e = 0; e < 4; ++e) sum += bf2f(v[e]) * Wspan[cl * 512 + k + e];
        }
        sum += bspan[cl];
        float mx = sum;
        mx = fmaxf(mx, __shfl_xor(mx, 1));
        mx = fmaxf(mx, __shfl_xor(mx, 2));
        float ex = expf(sum - mx);
        float den = ex + __shfl_xor(ex, 1);
        den += __shfl_xor(den, 2);
        out[(size_t)(r0 + row) * 4 + cl] = ex / den;
    }

    // ---- hoisted decoder pointers ----
    const int arow = r0 + m * 16 + l15;
    int colD[4];
    const u16* bpI[4];
    const u16* bpH[4];
    float bbD[4];
    #pragma unroll
    for (int i = 0; i < 4; ++i) {
        int q = nh * 4 + i;
        colD[i] = (q >> 1) * 512 + j0 + (q & 1) * 16 + l15;   // torch order i,f,g,o
        bpI[i] = Wih + (size_t)colD[i] * IN_ + l4 * 8;
        bpH[i] = Whh + (size_t)colD[i] * 512 + l4 * 8;
        bbD[i] = b_ih[colD[i]] + b_hh[colD[i]];
    }
    int colF[3];
    const u16* bpF[3];
    float bbF[3];
    const int nf = nh ? 1 : 2;
    #pragma unroll
    for (int i = 0; i < 3; ++i) {
        int q = nh * 2 + i;
        colF[i] = ct * 48 + q * 16 + l15;
        bpF[i] = Wfcin + (size_t)colF[i] * 512 + l4 * 8;
        bbF[i] = b_fcin[colF[i]];
    }

    // ================= decoder: 10 steps =================
    int pd = 0;
    for (int s = 0; s < 10; ++s) {
        const u16* apI = ib_[pd] + (size_t)arow * IN_ + l4 * 8;
        const u16* apH = hb_[pd] + (size_t)arow * 512 + l4 * 8;

        f32x4 dacc[4] = {};
        if (fastv) {
            // ib: 24 chunks in 3 batches of 8 (sc0 through XCD L2)
            #pragma unroll
            for (int g = 0; g < 3; ++g) {
                bf16x8 a8[8];
                #pragma unroll
                for (int i = 0; i < 8; ++i) a8[i] = ld_sc0_nb(apI + (g * 8 + i) * 32);
                drain_vm();
                #pragma unroll
                for (int i = 0; i < 8; ++i) {
                    int kc = g * 8 + i;
                    #pragma unroll
                    for (int j = 0; j < 4; ++j) {
                        bf16x8 b = *reinterpret_cast<const bf16x8*>(bpI[j] + kc * 32);
                        dacc[j] = __builtin_amdgcn_mfma_f32_16x16x32_bf16(a8[i], b, dacc[j], 0, 0, 0);
                    }
                }
            }
            // h: 16 chunks in 2 batches of 8
            #pragma unroll
            for (int g = 0; g < 2; ++g) {
                bf16x8 a8[8];
                #pragma unroll
                for (int i = 0; i < 8; ++i) a8[i] = ld_sc0_nb(apH + (g * 8 + i) * 32);
                drain_vm();
                #pragma unroll
                for (int i = 0; i < 8; ++i) {
                    int kc = g * 8 + i;
                    #pragma unroll
                    for (int j = 0; j < 4; ++j) {
                        bf16x8 b = *reinterpret_cast<const bf16x8*>(bpH[j] + kc * 32);
                        dacc[j] = __builtin_amdgcn_mfma_f32_16x16x32_bf16(a8[i], b, dacc[j], 0, 0, 0);
                    }
                }
            }
        } else {
            #pragma unroll 4
            for (int kc = 0; kc < 24; ++kc) {
                bf16x8 a = ld_state16(apI + kc * 32);
                #pragma unroll
                for (int i = 0; i < 4; ++i) {
                    bf16x8 b = *reinterpret_cast<const bf16x8*>(bpI[i] + kc * 32);
                    dacc[i] = __builtin_amdgcn_mfma_f32_16x16x32_bf16(a, b, dacc[i], 0, 0, 0);
                }
            }
            #pragma unroll 4
            for (int kc = 0; kc < 16; ++kc) {
                bf16x8 a = ld_state16(apH + kc * 32);
                #pragma unroll
                for (int i = 0; i < 4; ++i) {
                    bf16x8 b = *reinterpret_cast<const bf16x8*>(bpH[i] + kc * 32);
                    dacc[i] = __builtin_amdgcn_mfma_f32_16x16x32_bf16(a, b, dacc[i], 0, 0, 0);
                }
            }
        }
        #pragma unroll
        for (int i = 0; i < 4; ++i) {
            int q = nh * 4 + i;
            #pragma unroll
            for (int v = 0; v < 4; ++v) {
                int lr = m * 16 + l4 * 4 + v;
                gt[lr * GTP + (q >> 1) * 32 + (q & 1) * 16 + l15] = f2bf(dacc[i][v] + bbD[i]);
            }
        }
        __syncthreads();
        {
            u16x4 i4 = *reinterpret_cast<const u16x4*>(&gt[prow * GTP + 0 + pe0]);
            u16x4 f4 = *reinterpret_cast<const u16x4*>(&gt[prow * GTP + 32 + pe0]);
            u16x4 g4 = *reinterpret_cast<const u16x4*>(&gt[prow * GTP + 64 + pe0]);
            u16x4 o4 = *reinterpret_cast<const u16x4*>(&gt[prow * GTP + 96 + pe0]);
            size_t sidx = (size_t)(r0 + prow) * 512 + j0 + pe0;
            u16x4 cr4 = ld_state8(cb_[pd] + sidx);
            u16x4 hw, cw;
            #pragma unroll
            for (int e = 0; e < 4; ++e) {
                float ii = sigmoidf_(bf2f(i4[e]));
                float ff = sigmoidf_(bf2f(f4[e]));
                float gg = tanhf(bf2f(g4[e]));
                float oo = sigmoidf_(bf2f(o4[e]));
                float cn = ff * bf2f(cr4[e]) + ii * gg;
                float hn = oo * tanhf(cn);
                cw[e] = f2bf(cn); hw[e] = f2bf(hn);
            }
            if (fastv) {
                *reinterpret_cast<u64*>(hb_[pd ^ 1] + sidx) = __builtin_bit_cast(u64, hw);
                *reinterpret_cast<u64*>(cb_[pd ^ 1] + sidx) = __builtin_bit_cast(u64, cw);
            } else {
                st_agent_u64(hb_[pd ^ 1] + sidx, __builtin_bit_cast(u64, hw));
                st_agent_u64(cb_[pd ^ 1] + sidx, __builtin_bit_cast(u64, cw));
            }
        }
        gsig(); gwait();

        const u16* hp2 = hb_[pd ^ 1];
        if (s < 9) {
            const u16* ap2 = hp2 + (size_t)arow * 512 + l4 * 8;
            f32x4 facc[3] = {};
            if (fastv) {
                #pragma unroll
                for (int g = 0; g < 2; ++g) {
                    bf16x8 a8[8];
                    #pragma unroll
                    for (int i = 0; i < 8; ++i) a8[i] = ld_sc0_nb(ap2 + (g * 8 + i) * 32);
                    drain_vm();
                    #pragma unroll
                    for (int i = 0; i < 8; ++i) {
                        int kc = g * 8 + i;
                        for (int f = 0; f < nf; ++f) {
                            bf16x8 b = *reinterpret_cast<const bf16x8*>(bpF[f] + kc * 32);
                            facc[f] = __builtin_amdgcn_mfma_f32_16x16x32_bf16(a8[i], b, facc[f], 0, 0, 0);
                        }
                    }
                }
            } else {
                #pragma unroll 4
                for (int kc = 0; kc < 16; ++kc) {
                    bf16x8 a = ld_state16(ap2 + kc * 32);
                    for (int i = 0; i < nf; ++i) {
                        bf16x8 b = *reinterpret_cast<const bf16x8*>(bpF[i] + kc * 32);
                        facc[i] = __builtin_amdgcn_mfma_f32_16x16x32_bf16(a, b, facc[i], 0, 0, 0);
                    }
                }
            }
            for (int i = 0; i < nf; ++i) {
                #pragma unroll
                for (int v = 0; v < 4; ++v) {
                    int lr = m * 16 + l4 * 4 + v;
                    if (fastv)
                        ib_[pd ^ 1][(size_t)(r0 + lr) * IN_ + colF[i]] =
                            f2bf(fmaxf(facc[i][v] + bbF[i], 0.f));
                    else
                        st_agent_u16(ib_[pd ^ 1] + (size_t)(r0 + lr) * IN_ + colF[i],
                                     f2bf(fmaxf(facc[i][v] + bbF[i], 0.f)));
                }
            }
        }
        if (ct == 15 && tid < 128) {
            int row = tid >> 1, cl = tid & 1;
            const u16* hx = hp2 + (size_t)(r0 + row) * 512;
            float sum = 0.f;
            for (int k = 0; k < 512; k += 4) {
                u16x4 v = ld_state8(hx + k);
                #pragma unroll
                for (int e = 0; e < 4; ++e) sum += bf2f(v[e]) * Wfco[cl * 512 + k + e];
            }
            sum += b_fco[cl];
            float o2 = __shfl_xor(sum, 1);
            float mx = fmaxf(sum, o2);
            float ex = expf(sum - mx), eo = expf(o2 - mx);
            out[4096 + (size_t)(r0 + row) * 20 + s * 2 + cl] = ex / (ex + eo);
        }
        if (s < 9) { gsig(); gwait(); }
        pd ^= 1;
    }
}

// ---------------- launch ----------------

extern "C" void kernel_launch(void* const* d_in, const int* in_sizes, int n_in,
                              void* d_out, int out_size, void* d_ws, size_t ws_size,
                              hipStream_t stream) {
    (void)in_sizes; (void)n_in; (void)out_size;
    const float* sent    = (const float*)d_in[0];
    const float* timef   = (const float*)d_in[1];
    const float* Wd      = (const float*)d_in[2];
    const float* bd      = (const float*)d_in[3];
    const float* W_all   = (const float*)d_in[4];
    const float* b_all   = (const float*)d_in[5];
    const float* U_all   = (const float*)d_in[6];
    const float* b_U     = (const float*)d_in[7];
    const float* W_ih    = (const float*)d_in[8];
    const float* b_ih    = (const float*)d_in[9];
    const float* W_hh    = (const float*)d_in[10];
    const float* b_hh    = (const float*)d_in[11];
    const float* W_fc_in = (const float*)d_in[12];
    const float* b_fc_in = (const float*)d_in[13];
    const float* W_fc_out= (const float*)d_in[14];
    const float* b_fc_out= (const float*)d_in[15];
    const float* W_span  = (const float*)d_in[16];
    const float* b_span  = (const float*)d_in[17];
    float* out = (float*)d_out;

    char* ws = (char*)d_ws;
    size_t off = 0;
    auto alloc = [&](size_t bytes) -> void* {
        void* p = ws + off; off = (off + bytes + 255) & ~(size_t)255; return p;
    };
    float* tf     = (float*)alloc((size_t)B_ * T_ * 4);
    u16* Wall_b   = (u16*)alloc((size_t)G_ * H_ * 2);
    u16* Uall_b   = (u16*)alloc((size_t)G_ * IN_ * 2);
    u16* Wd_b     = (u16*)alloc((size_t)H_ * H_ * 2);
    u16* Wih_b    = (u16*)alloc((size_t)G_ * IN_ * 2);
    u16* Whh_b    = (u16*)alloc((size_t)G_ * H_ * 2);
    u16* Wfcin_b  = (u16*)alloc((size_t)IN_ * H_ * 2);
    float* xscale = (float*)alloc((size_t)B_ * T_ * 4);
    u16* hbuf0    = (u16*)alloc((size_t)B_ * H_ * 2);
    u16* hbuf1    = (u16*)alloc((size_t)B_ * H_ * 2);
    u16* cbuf0    = (u16*)alloc((size_t)B_ * H_ * 2);
    u16* cbuf1    = (u16*)alloc((size_t)B_ * H_ * 2);
    u16* ibuf0    = (u16*)alloc((size_t)B_ * IN_ * 2);
    u16* ibuf1    = (u16*)alloc((size_t)B_ * IN_ * 2);
    float* pn     = (float*)alloc((size_t)16 * 16 * 128 * 4);
    unsigned* flags  = (unsigned*)alloc(16 * 16 * 4);
    unsigned* flagsF = (unsigned*)alloc(16 * 16 * 4);
    unsigned* xcds   = (unsigned*)alloc(256 * 4);
    u16* XU       = (u16*)alloc((size_t)B_ * T_ * G_ * 2);
    u16* sentb    = (u16*)alloc((size_t)B_ * T_ * IN_ * 2);
    bool pathA = (off <= ws_size);

    // per-launch (= per-replay) re-init
    hipMemsetAsync(flags, 0, 16 * 16 * 4, stream);
    hipMemsetAsync(flagsF, 0, 16 * 16 * 4, stream);
    hipMemsetAsync(xcds, 0, 256 * 4, stream);
    hipMemsetAsync(pn, 0, (size_t)16 * 16 * 128 * 4, stream);
    hipMemsetAsync(hbuf0, 0, (size_t)B_ * H_ * 2, stream);
    hipMemsetAsync(cbuf0, 0, (size_t)B_ * H_ * 2, stream);
    hipMemsetAsync(ibuf0, 0, (size_t)B_ * IN_ * 2, stream);

    auto cvt = [&](const float* s, u16* d, int n) {
        cvt_f32_bf16<<<(n / 4 + 255) / 256, 256, 0, stream>>>(s, d, n);
    };
    cvt(W_all, Wall_b, G_ * H_);
    cvt(U_all, Uall_b, G_ * IN_);
    cvt(Wd, Wd_b, H_ * H_);
    cvt(W_ih, Wih_b, G_ * IN_);
    cvt(W_hh, Whh_b, G_ * H_);
    cvt(W_fc_in, Wfcin_b, IN_ * H_);

    tf_kernel<<<B_, 128, 0, stream>>>(timef, tf);

    if (pathA) {
        prep_sentb<<<B_ * T_, 256, 0, stream>>>(sent, sentb);
        xu_gemm<0><<<(B_ * T_ / 128) * (G_ / 128), 256, 0, stream>>>(
            sentb, nullptr, Uall_b, b_all, b_U, XU);
    } else {
        xscale_kernel<<<B_ * T_, 256, 0, stream>>>(sent, xscale);
        xu_gemm<1><<<(B_ * T_ / 128) * (G_ / 128), 256, 0, stream>>>(
            sent, xscale, Uall_b, b_all, b_U, XU);
    }

    persistent10<<<GRIDN, 512, 0, stream>>>(
        XU, tf, Wall_b, Wd_b, bd, Wih_b, Whh_b, b_ih, b_hh,
        Wfcin_b, b_fc_in, W_fc_out, b_fc_out, W_span, b_span,
        hbuf0, hbuf1, cbuf0, cbuf1, ibuf0, ibuf1,
        pn, flags, flagsF, xcds, out);
}